// Round 3
// baseline (273.152 us; speedup 1.0000x reference)
//
#include <hip/hip_runtime.h>
#include <hip/hip_bf16.h>

#define B_   8
#define C_   128
#define HW_  16384
#define N_   16
#define EPS_ 1e-7f

typedef unsigned short u16;
typedef __attribute__((ext_vector_type(8))) short s8v;
typedef __attribute__((ext_vector_type(4))) short s4v;
typedef __attribute__((ext_vector_type(4))) float f4v;

__device__ __forceinline__ u16 f2b(float f) {
  union { __hip_bfloat16 b; u16 u; } cv; cv.b = __float2bfloat16(f); return cv.u;
}
__device__ __forceinline__ float b2f(u16 u) {
  union { float f; unsigned int i; } cv; cv.i = ((unsigned int)u) << 16; return cv.f;
}
__device__ __forceinline__ float wredsum(float v) {
#pragma unroll
  for (int o = 32; o > 0; o >>= 1) v += __shfl_xor(v, o, 64);
  return v;
}
__device__ __forceinline__ float wredmax(float v) {
#pragma unroll
  for (int o = 32; o > 0; o >>= 1) v = fmaxf(v, __shfl_xor(v, o, 64));
  return v;
}

// ---------------- Kernel 1: per-batch partial Gram + fused misc -------------
// grid (65, 8): blockIdx.x<64 -> Gram chunks (256 pos each, 2 k-tiles of 128,
// register-pipelined staging, 16 float4 in flight). blockIdx.x==64 -> misc
// (b0: u colsums, b1: orth loss, b2: Wo->bf16).
#define XS_ 136
__global__ __launch_bounds__(256, 2) void k_gram(
    const float* __restrict__ x, float* __restrict__ pbuf, float* __restrict__ psx,
    const float* __restrict__ Wsa, const float* __restrict__ kn,
    const float* __restrict__ Wo, float* __restrict__ u,
    float* __restrict__ loss_out, u16* __restrict__ wo_bf) {
  __shared__ u16 Xb[C_ * XS_];
  const int tid = threadIdx.x;
  const int b = blockIdx.y;

  if (blockIdx.x == 64) {  // ---- misc blocks ----
    if (b == 0) {          // u[r] = column sums of Wsa
      if (tid < C_) {
        float s = 0.f;
        for (int i = 0; i < C_; ++i) s += Wsa[i * C_ + tid];
        u[tid] = s;
      }
    } else if (b == 1) {   // orth loss
      float* smf = (float*)Xb;          // reuse LDS: [0..15]=nrm, [16..19]=rb4
      const int i = tid >> 4, j = tid & 15;
      float s = 0.f;
      for (int c = 0; c < C_; ++c) s += kn[i * C_ + c] * kn[j * C_ + c];
      if (i == j) smf[i] = sqrtf(s);
      __syncthreads();
      float l = s / (smf[i] * smf[j] + EPS_) - (i == j ? 1.f : 0.f);
      float wv = wredsum(l * l);
      if ((tid & 63) == 0) smf[16 + (tid >> 6)] = wv;
      __syncthreads();
      if (tid == 0) loss_out[0] = 0.1f * logf(smf[16] + smf[17] + smf[18] + smf[19] + 1.f);
    } else if (b == 2) {   // Wo -> bf16
#pragma unroll
      for (int j = 0; j < 16; ++j) {
        int f = tid + 256 * j;
        float4 v = ((const float4*)Wo)[f];
        s4v s; s[0] = (short)f2b(v.x); s[1] = (short)f2b(v.y);
        s[2] = (short)f2b(v.z); s[3] = (short)f2b(v.w);
        ((s4v*)wo_bf)[f] = s;
      }
    }
    return;
  }

  const int p0 = blockIdx.x * 256;
  const int lane = tid & 63;
  const int w = tid >> 6;
  const int m = lane & 15, q = lane >> 4;
  const int rb = (w >> 1) * 64, cb = (w & 1) * 64;

  f4v acc[4][4];
#pragma unroll
  for (int a = 0; a < 4; ++a)
#pragma unroll
    for (int c2 = 0; c2 < 4; ++c2) acc[a][c2] = (f4v){0.f, 0.f, 0.f, 0.f};

  float sxp = 0.f;
  const float* xb = x + (size_t)b * C_ * HW_;
  const float* ro = xb + (size_t)(tid >> 5) * HW_ + p0 + 4 * (tid & 31);

  float4 v[16];
  // bulk-load tile 0 (16 outstanding float4 loads)
#pragma unroll
  for (int j = 0; j < 16; ++j) v[j] = *(const float4*)(ro + (size_t)(8 * j) * HW_);

#pragma unroll
  for (int t = 0; t < 2; ++t) {
    // convert + LDS write
#pragma unroll
    for (int j = 0; j < 16; ++j) {
      int c = (tid >> 5) + 8 * j;
      s4v s; s[0] = (short)f2b(v[j].x); s[1] = (short)f2b(v[j].y);
      s[2] = (short)f2b(v[j].z); s[3] = (short)f2b(v[j].w);
      *(s4v*)(&Xb[c * XS_ + 4 * (tid & 31)]) = s;
    }
    __syncthreads();
    if (t == 0) {  // prefetch tile 1 under tile-0 MFMA
#pragma unroll
      for (int j = 0; j < 16; ++j) v[j] = *(const float4*)(ro + (size_t)(8 * j) * HW_ + 128);
    }
    if (tid < C_) {
#pragma unroll
      for (int kk = 0; kk < 16; ++kk) {
        s8v vv = *(const s8v*)(&Xb[tid * XS_ + 8 * kk]);
#pragma unroll
        for (int e = 0; e < 8; ++e) sxp += b2f((u16)vv[e]);
      }
    }
#pragma unroll
    for (int s = 0; s < 4; ++s) {
      const int k0 = 32 * s;
      s8v Af[4], Bf[4];
#pragma unroll
      for (int a = 0; a < 4; ++a)
        Af[a] = *(const s8v*)(&Xb[(rb + 16 * a + m) * XS_ + k0 + 8 * q]);
#pragma unroll
      for (int c2 = 0; c2 < 4; ++c2)
        Bf[c2] = *(const s8v*)(&Xb[(cb + 16 * c2 + m) * XS_ + k0 + 8 * q]);
#pragma unroll
      for (int a = 0; a < 4; ++a)
#pragma unroll
        for (int c2 = 0; c2 < 4; ++c2)
          acc[a][c2] = __builtin_amdgcn_mfma_f32_16x16x32_bf16(Af[a], Bf[c2], acc[a][c2], 0, 0, 0);
    }
    __syncthreads();
  }

  float* pg = pbuf + ((size_t)(blockIdx.x * B_ + b) << 14);
#pragma unroll
  for (int a = 0; a < 4; ++a)
#pragma unroll
    for (int c2 = 0; c2 < 4; ++c2)
#pragma unroll
      for (int r = 0; r < 4; ++r) {
        int row = rb + 16 * a + 4 * q + r;
        int col = cb + 16 * c2 + m;
        pg[row * C_ + col] = acc[a][c2][r];
      }
  if (tid < C_) psx[(blockIdx.x * B_ + b) * C_ + tid] = sxp;
}

// ---------------- reduce 64 partials -> G, sx (float4) ----------------------
__global__ __launch_bounds__(256) void k_greduce(const float4* __restrict__ pbuf4,
                                                 const float* __restrict__ psx,
                                                 float4* __restrict__ G4,
                                                 float* __restrict__ sx) {
  const int blk = blockIdx.x;
  if (blk < 128) {
    const int gid = blk * 256 + threadIdx.x;  // [0, 32768)
    const int b = gid >> 12, idx4 = gid & 4095;
    float4 s = {0.f, 0.f, 0.f, 0.f};
#pragma unroll 16
    for (int ch = 0; ch < 64; ++ch) {
      float4 p = pbuf4[((size_t)(ch * B_ + b) << 12) + idx4];
      s.x += p.x; s.y += p.y; s.z += p.z; s.w += p.w;
    }
    G4[gid] = s;
  } else {
    const int tt = (blk - 128) * 256 + threadIdx.x;  // [0, 1024)
    const int b = tt >> 7, c = tt & 127;
    float s = 0.f;
#pragma unroll 16
    for (int ch = 0; ch < 64; ++ch) s += psx[(ch * B_ + b) * C_ + c];
    sx[tt] = s;
  }
}

// ---------------- Kernel 2: per-(batch, column) G-derived quantities --------
__global__ __launch_bounds__(64) void k_cols(
    const float* __restrict__ G, const float* __restrict__ sx,
    const float* __restrict__ Wr, const float* __restrict__ Wsa,
    const float* __restrict__ Wo, const float* __restrict__ kn,
    const float* __restrict__ u,
    float* diagR, float* diagSA, float* colsumSA, float* diagO,
    float* prv, float* psav, float* pov, float* rel, float* diagN, float* ksx) {
  const int b = blockIdx.y;
  const int col = blockIdx.x;
  const int lane = threadIdx.x;
  const float* Gb = G + b * C_ * C_;
  const float4* g0 = (const float4*)(Gb + lane * C_);
  const float4* g1 = (const float4*)(Gb + (64 + lane) * C_);
  const float sx0 = sx[b * C_ + lane], sx1 = sx[b * C_ + 64 + lane];

  if (col < C_) {
    const float4* wr = (const float4*)(Wr + col * C_);
    const float4* wa = (const float4*)(Wsa + col * C_);
    const float4* wo = (const float4*)(Wo + col * C_);
    float t0r = 0, t1r = 0, t0a = 0, t1a = 0, t0o = 0, t1o = 0;
    for (int c = 0; c < 32; ++c) {
      float4 a0 = g0[c], a1 = g1[c];
      float4 vr = wr[c], va = wa[c], vo = wo[c];
      t0r += a0.x * vr.x + a0.y * vr.y + a0.z * vr.z + a0.w * vr.w;
      t1r += a1.x * vr.x + a1.y * vr.y + a1.z * vr.z + a1.w * vr.w;
      t0a += a0.x * va.x + a0.y * va.y + a0.z * va.z + a0.w * va.w;
      t1a += a1.x * va.x + a1.y * va.y + a1.z * va.z + a1.w * va.w;
      t0o += a0.x * vo.x + a0.y * vo.y + a0.z * vo.z + a0.w * vo.w;
      t1o += a1.x * vo.x + a1.y * vo.y + a1.z * vo.z + a1.w * vo.w;
    }
    float wr0 = Wr[col * C_ + lane], wr1 = Wr[col * C_ + 64 + lane];
    float wa0 = Wsa[col * C_ + lane], wa1 = Wsa[col * C_ + 64 + lane];
    float wo0 = Wo[col * C_ + lane], wo1 = Wo[col * C_ + 64 + lane];
    float u0 = u[lane], u1 = u[64 + lane];
    float dR = wredsum(wr0 * t0r + wr1 * t1r);
    float pR = wredsum(wr0 * sx0 + wr1 * sx1);
    float dA = wredsum(wa0 * t0a + wa1 * t1a);
    float cA = wredsum(u0 * t0a + u1 * t1a);
    float pA = wredsum(wa0 * sx0 + wa1 * sx1);
    float dO = wredsum(wo0 * t0o + wo1 * t1o);
    float pO = wredsum(wo0 * sx0 + wo1 * sx1);
    float rl[N_];
#pragma unroll
    for (int n = 0; n < N_; ++n)
      rl[n] = wredsum(kn[n * C_ + lane] * t0r + kn[n * C_ + 64 + lane] * t1r);
    if (lane == 0) {
      diagR[b * C_ + col] = dR;  prv[b * C_ + col] = pR;
      diagSA[b * C_ + col] = dA; colsumSA[b * C_ + col] = cA; psav[b * C_ + col] = pA;
      diagO[b * C_ + col] = dO;  pov[b * C_ + col] = pO;
      for (int n = 0; n < N_; ++n) rel[(b * N_ + n) * C_ + col] = rl[n];
    }
  } else {
    const int n = col - C_;
    const float4* wk = (const float4*)(kn + n * C_);
    float t0 = 0, t1 = 0;
    for (int c = 0; c < 32; ++c) {
      float4 a0 = g0[c], a1 = g1[c], vk = wk[c];
      t0 += a0.x * vk.x + a0.y * vk.y + a0.z * vk.z + a0.w * vk.w;
      t1 += a1.x * vk.x + a1.y * vk.y + a1.z * vk.z + a1.w * vk.w;
    }
    float k0v = kn[n * C_ + lane], k1v = kn[n * C_ + 64 + lane];
    float dN = wredsum(k0v * t0 + k1v * t1);
    float kx = wredsum(k0v * sx0 + k1v * sx1);
    if (lane == 0) { diagN[b * N_ + n] = dN; ksx[b * N_ + n] = kx; }
  }
}

// ---------------- Kernel 3: per-batch assembly -> A[b,c], B[b,c] ------------
__global__ __launch_bounds__(128) void k_asm(
    const float* diagR, const float* diagSA, const float* colsumSA, const float* diagO,
    const float* prv, const float* psav, const float* pov,
    const float* rel, const float* diagN, const float* ksx,
    const float* br, const float* bo, const float* bsa, const float* alpha,
    float* Aout, float* Bout) {
  const int b = blockIdx.x;
  const int t = threadIdx.x;
  __shared__ float rb2[2];
  __shared__ float att_s[N_][C_ + 1];
  __shared__ float s1_s[C_], s2_s[C_];
  __shared__ float inv_s[N_], fmi_s[N_];
  const float hw = (float)HW_;
  const float bsa_c = bsa[t], br_c = br[t], bo_c = bo[t];
  const float psa_c = psav[b * C_ + t], pr_c = prv[b * C_ + t], po_c = pov[b * C_ + t];

  float bsum, psum, mx, ssum;
  { float wv = wredsum(bsa_c); if ((t & 63) == 0) rb2[t >> 6] = wv; __syncthreads();
    bsum = rb2[0] + rb2[1]; __syncthreads(); }
  { float wv = wredsum(psa_c); if ((t & 63) == 0) rb2[t >> 6] = wv; __syncthreads();
    psum = rb2[0] + rb2[1]; __syncthreads(); }

  const float nxr = sqrtf(fmaxf(diagR[b * C_ + t] + 2.f * br_c * pr_c + hw * br_c * br_c, 0.f));
  s1_s[t] = po_c + hw * bo_c;
  s2_s[t] = diagO[b * C_ + t] + 2.f * bo_c * po_c + hw * bo_c * bo_c;
  const float colsum = colsumSA[b * C_ + t] + bsum * psa_c + bsa_c * (psum + hw * bsum);
  const float diagv = diagSA[b * C_ + t] + 2.f * bsa_c * psa_c + hw * bsa_c * bsa_c;
  const float fm = (colsum - diagv) * (1.f / (float)C_);

  { float wv = wredmax(fm); if ((t & 63) == 0) rb2[t >> 6] = wv; __syncthreads();
    mx = fmaxf(rb2[0], rb2[1]); __syncthreads(); }
  const float ee = expf(fm - mx);
  { float wv = wredsum(ee); if ((t & 63) == 0) rb2[t >> 6] = wv; __syncthreads();
    ssum = rb2[0] + rb2[1]; __syncthreads(); }
  const float reg = ee / ssum;

  float r[N_];
  float rmax = -1e30f;
#pragma unroll
  for (int n = 0; n < N_; ++n) {
    float al = fminf(fmaxf(alpha[n], 0.f), 1.f);
    float nxn = sqrtf(fmaxf(diagN[b * N_ + n], 0.f));
    float rv = (rel[(b * N_ + n) * C_ + t] + br_c * ksx[b * N_ + n]) / (nxn * nxr + EPS_) + al * reg;
    r[n] = rv; rmax = fmaxf(rmax, rv);
  }
  float es = 0.f;
#pragma unroll
  for (int n = 0; n < N_; ++n) { r[n] = expf(r[n] - rmax); es += r[n]; }
  const float ies = 1.f / es;
#pragma unroll
  for (int n = 0; n < N_; ++n) att_s[n][t] = r[n] * ies;
  __syncthreads();

  if (t < N_) {
    float sa = 0.f, sh = 0.f, sq = 0.f;
    for (int c = 0; c < C_; ++c) {
      float a = att_s[t][c];
      sa += a; sh += a * s1_s[c]; sq += a * a * s2_s[c];
    }
    float cnt = sa * hw + EPS_;
    float fmean = sh / cnt;
    float sqv = sq - 2.f * fmean * sh + fmean * fmean * ((float)C_ * hw);
    float fstd = sqrtf(fmaxf(sqv, 0.f) / cnt);
    float inv = 1.f / (fstd + EPS_);
    inv_s[t] = inv; fmi_s[t] = fmean * inv;
  }
  __syncthreads();

  float Ac = 0.f, Bc = 0.f;
#pragma unroll
  for (int n = 0; n < N_; ++n) { float a = att_s[n][t]; Ac += a * inv_s[n]; Bc += a * fmi_s[n]; }
  Aout[b * C_ + t] = Ac; Bout[b * C_ + t] = Bc;
}

// ---------------- Kernel 4: out = x + sigma*((Wo x + bo)*A - B) -------------
// grid (64, 8), 256 threads, LB(256,2). A-fragments of bf16-Wo live entirely
// in registers (128 VGPRs, loaded once). LDS only holds the 64-pos transposed
// x tile. x loads register-prefetched across pt iterations.
#define XT_ 136
__global__ __launch_bounds__(256, 2) void k_out(
    const float* __restrict__ x, const u16* __restrict__ wo_bf,
    const float* __restrict__ bo, const float* __restrict__ Aws,
    const float* __restrict__ Bws, const float* __restrict__ sig,
    float* __restrict__ out) {
  const int b = blockIdx.y;
  __shared__ u16 Xt[64 * XT_];
  __shared__ float As[C_], Bs[C_], bos[C_];
  const int tid = threadIdx.x, lane = tid & 63, w = tid >> 6;
  const int n = lane & 15, q = lane >> 4;

  if (tid < C_) { As[tid] = Aws[b * C_ + tid]; Bs[tid] = Bws[b * C_ + tid]; bos[tid] = bo[tid]; }
  const float sg = sig[0];

  // A-fragments: af[a][s] = Wo_bf16[16a+n][32s+8q .. +7]
  s8v af[8][4];
#pragma unroll
  for (int a = 0; a < 8; ++a)
#pragma unroll
    for (int s = 0; s < 4; ++s)
      af[a][s] = *(const s8v*)(wo_bf + (16 * a + n) * C_ + 32 * s + 8 * q);

  const float* xb = x + (size_t)b * C_ * HW_;
  float* ob = out + (size_t)b * C_ * HW_;
  const int pq = tid & 15;           // cell geometry (cc in {0,1})
  const int c4a = tid >> 4;          // cell 0: c4 = c4a; cell 1: c4 = 16 + c4a

  float4 v[8];
  {
    const int p0 = blockIdx.x * 256;
#pragma unroll
    for (int cc = 0; cc < 2; ++cc) {
      const float* src = xb + (size_t)(4 * (16 * cc + c4a)) * HW_ + p0 + 4 * pq;
#pragma unroll
      for (int r2 = 0; r2 < 4; ++r2) v[4 * cc + r2] = *(const float4*)(src + (size_t)r2 * HW_);
    }
  }

#pragma unroll
  for (int pt = 0; pt < 4; ++pt) {
    const int p0 = blockIdx.x * 256 + pt * 64;
    // transpose + convert + LDS write
#pragma unroll
    for (int cc = 0; cc < 2; ++cc) {
      const int c4 = 16 * cc + c4a;
      float4 v0 = v[4 * cc + 0], v1 = v[4 * cc + 1], v2 = v[4 * cc + 2], v3 = v[4 * cc + 3];
      s4v s0, s1, s2, s3;
      s0[0] = (short)f2b(v0.x); s0[1] = (short)f2b(v1.x); s0[2] = (short)f2b(v2.x); s0[3] = (short)f2b(v3.x);
      s1[0] = (short)f2b(v0.y); s1[1] = (short)f2b(v1.y); s1[2] = (short)f2b(v2.y); s1[3] = (short)f2b(v3.y);
      s2[0] = (short)f2b(v0.z); s2[1] = (short)f2b(v1.z); s2[2] = (short)f2b(v2.z); s2[3] = (short)f2b(v3.z);
      s3[0] = (short)f2b(v0.w); s3[1] = (short)f2b(v1.w); s3[2] = (short)f2b(v2.w); s3[3] = (short)f2b(v3.w);
      *(s4v*)(&Xt[(4 * pq + 0) * XT_ + 4 * c4]) = s0;
      *(s4v*)(&Xt[(4 * pq + 1) * XT_ + 4 * c4]) = s1;
      *(s4v*)(&Xt[(4 * pq + 2) * XT_ + 4 * c4]) = s2;
      *(s4v*)(&Xt[(4 * pq + 3) * XT_ + 4 * c4]) = s3;
    }
    __syncthreads();
    if (pt < 3) {  // prefetch next tile under MFMA
      const int pn = p0 + 64;
#pragma unroll
      for (int cc = 0; cc < 2; ++cc) {
        const float* src = xb + (size_t)(4 * (16 * cc + c4a)) * HW_ + pn + 4 * pq;
#pragma unroll
        for (int r2 = 0; r2 < 4; ++r2) v[4 * cc + r2] = *(const float4*)(src + (size_t)r2 * HW_);
      }
    }

    f4v acc[8];
#pragma unroll
    for (int a = 0; a < 8; ++a) acc[a] = (f4v){0.f, 0.f, 0.f, 0.f};
#pragma unroll
    for (int s = 0; s < 4; ++s) {
      s8v bfr = *(const s8v*)(&Xt[(w * 16 + n) * XT_ + 32 * s + 8 * q]);
#pragma unroll
      for (int a = 0; a < 8; ++a)
        acc[a] = __builtin_amdgcn_mfma_f32_16x16x32_bf16(af[a][s], bfr, acc[a], 0, 0, 0);
    }

#pragma unroll
    for (int a = 0; a < 8; ++a)
#pragma unroll
      for (int r = 0; r < 4; ++r) {
        int o = 16 * a + 4 * q + r;
        size_t idx = (size_t)o * HW_ + p0 + w * 16 + n;
        float xo = acc[a][r] + bos[o];
        ob[idx] = xb[idx] + sg * (xo * As[o] - Bs[o]);
      }
    __syncthreads();
  }
}

extern "C" void kernel_launch(void* const* d_in, const int* in_sizes, int n_in,
                              void* d_out, int out_size, void* d_ws, size_t ws_size,
                              hipStream_t stream) {
  (void)in_sizes; (void)n_in; (void)out_size; (void)ws_size;
  const float* x     = (const float*)d_in[0];
  const float* Wsa   = (const float*)d_in[1];
  const float* bsa   = (const float*)d_in[2];
  const float* Wr    = (const float*)d_in[3];
  const float* br    = (const float*)d_in[4];
  const float* kn    = (const float*)d_in[5];
  const float* Wo    = (const float*)d_in[6];
  const float* bo    = (const float*)d_in[7];
  const float* alpha = (const float*)d_in[8];
  const float* sigma = (const float*)d_in[9];
  float* out = (float*)d_out;
  float* ws  = (float*)d_ws;

  float* G        = ws;            // 131072
  float* sx       = ws + 131072;   // 1024
  float* diagR    = ws + 132096;   // 1024
  float* diagSA   = ws + 133120;   // 1024
  float* colsumSA = ws + 134144;   // 1024
  float* diagO    = ws + 135168;   // 1024
  float* prv      = ws + 136192;   // 1024
  float* psav     = ws + 137216;   // 1024
  float* pov      = ws + 138240;   // 1024
  float* rel      = ws + 139264;   // 16384
  float* diagN    = ws + 155648;   // 128
  float* ksx      = ws + 155776;   // 128
  float* u        = ws + 155904;   // 128
  float* Aw       = ws + 156032;   // 1024
  float* Bw       = ws + 157056;   // 1024
  u16*   wo_bf    = (u16*)(ws + 158080);  // 16384 u16 = 8192 floats

  // d_out doubles as scratch for Gram partials until k_out overwrites it:
  float* pbuf = out;               // 64*8*16384 = 8388608 floats
  float* psx  = out + 8388608;     // 64*8*128   = 65536 floats

  k_gram<<<dim3(65, 8), 256, 0, stream>>>(x, pbuf, psx, Wsa, kn, Wo, u,
      out + (size_t)B_ * C_ * HW_, wo_bf);
  k_greduce<<<132, 256, 0, stream>>>((const float4*)pbuf, psx, (float4*)G, sx);
  k_cols<<<dim3(144, 8), 64, 0, stream>>>(G, sx, Wr, Wsa, Wo, kn, u,
      diagR, diagSA, colsumSA, diagO, prv, psav, pov, rel, diagN, ksx);
  k_asm<<<8, 128, 0, stream>>>(diagR, diagSA, colsumSA, diagO, prv, psav, pov,
      rel, diagN, ksx, br, bo, bsa, alpha, Aw, Bw);
  k_out<<<dim3(64, 8), 256, 0, stream>>>(x, wo_bf, bo, Aw, Bw, sigma, out);
}

// Round 4
// 186.343 us; speedup vs baseline: 1.4659x; 1.4659x over previous
//
#include <hip/hip_runtime.h>
#include <hip/hip_bf16.h>

#define B_   8
#define C_   128
#define HW_  16384
#define N_   16
#define EPS_ 1e-7f

typedef unsigned short u16;
typedef __attribute__((ext_vector_type(8))) short s8v;
typedef __attribute__((ext_vector_type(4))) short s4v;
typedef __attribute__((ext_vector_type(4))) float f4v;

__device__ __forceinline__ u16 f2b(float f) {
  union { __hip_bfloat16 b; u16 u; } cv; cv.b = __float2bfloat16(f); return cv.u;
}
__device__ __forceinline__ float b2f(u16 u) {
  union { float f; unsigned int i; } cv; cv.i = ((unsigned int)u) << 16; return cv.f;
}
__device__ __forceinline__ float wredsum(float v) {
#pragma unroll
  for (int o = 32; o > 0; o >>= 1) v += __shfl_xor(v, o, 64);
  return v;
}
__device__ __forceinline__ float wredmax(float v) {
#pragma unroll
  for (int o = 32; o > 0; o >>= 1) v = fmaxf(v, __shfl_xor(v, o, 64));
  return v;
}

// ---------------- Kernel 1: per-batch partial Gram + fused misc -------------
// grid (65, 8): blockIdx.x<64 -> Gram chunks (256 pos each, 2 k-tiles of 128,
// register-pipelined staging, 16 float4 in flight). blockIdx.x==64 -> misc
// (b0: u colsums, b1: orth loss, b2: Wo->bf16).
#define XS_ 136
__global__ __launch_bounds__(256, 2) void k_gram(
    const float* __restrict__ x, float* __restrict__ pbuf, float* __restrict__ psx,
    const float* __restrict__ Wsa, const float* __restrict__ kn,
    const float* __restrict__ Wo, float* __restrict__ u,
    float* __restrict__ loss_out, u16* __restrict__ wo_bf) {
  __shared__ u16 Xb[C_ * XS_];
  const int tid = threadIdx.x;
  const int b = blockIdx.y;

  if (blockIdx.x == 64) {  // ---- misc blocks ----
    if (b == 0) {          // u[r] = column sums of Wsa
      if (tid < C_) {
        float s = 0.f;
        for (int i = 0; i < C_; ++i) s += Wsa[i * C_ + tid];
        u[tid] = s;
      }
    } else if (b == 1) {   // orth loss
      float* smf = (float*)Xb;          // reuse LDS: [0..15]=nrm, [16..19]=rb4
      const int i = tid >> 4, j = tid & 15;
      float s = 0.f;
      for (int c = 0; c < C_; ++c) s += kn[i * C_ + c] * kn[j * C_ + c];
      if (i == j) smf[i] = sqrtf(s);
      __syncthreads();
      float l = s / (smf[i] * smf[j] + EPS_) - (i == j ? 1.f : 0.f);
      float wv = wredsum(l * l);
      if ((tid & 63) == 0) smf[16 + (tid >> 6)] = wv;
      __syncthreads();
      if (tid == 0) loss_out[0] = 0.1f * logf(smf[16] + smf[17] + smf[18] + smf[19] + 1.f);
    } else if (b == 2) {   // Wo -> bf16
#pragma unroll
      for (int j = 0; j < 16; ++j) {
        int f = tid + 256 * j;
        float4 v = ((const float4*)Wo)[f];
        s4v s; s[0] = (short)f2b(v.x); s[1] = (short)f2b(v.y);
        s[2] = (short)f2b(v.z); s[3] = (short)f2b(v.w);
        ((s4v*)wo_bf)[f] = s;
      }
    }
    return;
  }

  const int p0 = blockIdx.x * 256;
  const int lane = tid & 63;
  const int w = tid >> 6;
  const int m = lane & 15, q = lane >> 4;
  const int rb = (w >> 1) * 64, cb = (w & 1) * 64;

  f4v acc[4][4];
#pragma unroll
  for (int a = 0; a < 4; ++a)
#pragma unroll
    for (int c2 = 0; c2 < 4; ++c2) acc[a][c2] = (f4v){0.f, 0.f, 0.f, 0.f};

  float sxp = 0.f;
  const float* xb = x + (size_t)b * C_ * HW_;
  const float* ro = xb + (size_t)(tid >> 5) * HW_ + p0 + 4 * (tid & 31);

  float4 v[16];
  // bulk-load tile 0 (16 outstanding float4 loads)
#pragma unroll
  for (int j = 0; j < 16; ++j) v[j] = *(const float4*)(ro + (size_t)(8 * j) * HW_);

#pragma unroll
  for (int t = 0; t < 2; ++t) {
    // convert + LDS write
#pragma unroll
    for (int j = 0; j < 16; ++j) {
      int c = (tid >> 5) + 8 * j;
      s4v s; s[0] = (short)f2b(v[j].x); s[1] = (short)f2b(v[j].y);
      s[2] = (short)f2b(v[j].z); s[3] = (short)f2b(v[j].w);
      *(s4v*)(&Xb[c * XS_ + 4 * (tid & 31)]) = s;
    }
    __syncthreads();
    if (t == 0) {  // prefetch tile 1 under tile-0 MFMA
#pragma unroll
      for (int j = 0; j < 16; ++j) v[j] = *(const float4*)(ro + (size_t)(8 * j) * HW_ + 128);
    }
    if (tid < C_) {
#pragma unroll
      for (int kk = 0; kk < 16; ++kk) {
        s8v vv = *(const s8v*)(&Xb[tid * XS_ + 8 * kk]);
#pragma unroll
        for (int e = 0; e < 8; ++e) sxp += b2f((u16)vv[e]);
      }
    }
#pragma unroll
    for (int s = 0; s < 4; ++s) {
      const int k0 = 32 * s;
      s8v Af[4], Bf[4];
#pragma unroll
      for (int a = 0; a < 4; ++a)
        Af[a] = *(const s8v*)(&Xb[(rb + 16 * a + m) * XS_ + k0 + 8 * q]);
#pragma unroll
      for (int c2 = 0; c2 < 4; ++c2)
        Bf[c2] = *(const s8v*)(&Xb[(cb + 16 * c2 + m) * XS_ + k0 + 8 * q]);
#pragma unroll
      for (int a = 0; a < 4; ++a)
#pragma unroll
        for (int c2 = 0; c2 < 4; ++c2)
          acc[a][c2] = __builtin_amdgcn_mfma_f32_16x16x32_bf16(Af[a], Bf[c2], acc[a][c2], 0, 0, 0);
    }
    __syncthreads();
  }

  float* pg = pbuf + ((size_t)(blockIdx.x * B_ + b) << 14);
#pragma unroll
  for (int a = 0; a < 4; ++a)
#pragma unroll
    for (int c2 = 0; c2 < 4; ++c2)
#pragma unroll
      for (int r = 0; r < 4; ++r) {
        int row = rb + 16 * a + 4 * q + r;
        int col = cb + 16 * c2 + m;
        pg[row * C_ + col] = acc[a][c2][r];
      }
  if (tid < C_) psx[(blockIdx.x * B_ + b) * C_ + tid] = sxp;
}

// ---------------- reduce 64 partials -> G, sx (float4) ----------------------
__global__ __launch_bounds__(256) void k_greduce(const float4* __restrict__ pbuf4,
                                                 const float* __restrict__ psx,
                                                 float4* __restrict__ G4,
                                                 float* __restrict__ sx) {
  const int blk = blockIdx.x;
  if (blk < 128) {
    const int gid = blk * 256 + threadIdx.x;  // [0, 32768)
    const int b = gid >> 12, idx4 = gid & 4095;
    float4 s = {0.f, 0.f, 0.f, 0.f};
#pragma unroll 16
    for (int ch = 0; ch < 64; ++ch) {
      float4 p = pbuf4[((size_t)(ch * B_ + b) << 12) + idx4];
      s.x += p.x; s.y += p.y; s.z += p.z; s.w += p.w;
    }
    G4[gid] = s;
  } else {
    const int tt = (blk - 128) * 256 + threadIdx.x;  // [0, 1024)
    const int b = tt >> 7, c = tt & 127;
    float s = 0.f;
#pragma unroll 16
    for (int ch = 0; ch < 64; ++ch) s += psx[(ch * B_ + b) * C_ + c];
    sx[tt] = s;
  }
}

// ---------------- Kernel 2: per-(batch, column) G-derived quantities --------
__global__ __launch_bounds__(64) void k_cols(
    const float* __restrict__ G, const float* __restrict__ sx,
    const float* __restrict__ Wr, const float* __restrict__ Wsa,
    const float* __restrict__ Wo, const float* __restrict__ kn,
    const float* __restrict__ u,
    float* diagR, float* diagSA, float* colsumSA, float* diagO,
    float* prv, float* psav, float* pov, float* rel, float* diagN, float* ksx) {
  const int b = blockIdx.y;
  const int col = blockIdx.x;
  const int lane = threadIdx.x;
  const float* Gb = G + b * C_ * C_;
  const float4* g0 = (const float4*)(Gb + lane * C_);
  const float4* g1 = (const float4*)(Gb + (64 + lane) * C_);
  const float sx0 = sx[b * C_ + lane], sx1 = sx[b * C_ + 64 + lane];

  if (col < C_) {
    const float4* wr = (const float4*)(Wr + col * C_);
    const float4* wa = (const float4*)(Wsa + col * C_);
    const float4* wo = (const float4*)(Wo + col * C_);
    float t0r = 0, t1r = 0, t0a = 0, t1a = 0, t0o = 0, t1o = 0;
    for (int c = 0; c < 32; ++c) {
      float4 a0 = g0[c], a1 = g1[c];
      float4 vr = wr[c], va = wa[c], vo = wo[c];
      t0r += a0.x * vr.x + a0.y * vr.y + a0.z * vr.z + a0.w * vr.w;
      t1r += a1.x * vr.x + a1.y * vr.y + a1.z * vr.z + a1.w * vr.w;
      t0a += a0.x * va.x + a0.y * va.y + a0.z * va.z + a0.w * va.w;
      t1a += a1.x * va.x + a1.y * va.y + a1.z * va.z + a1.w * va.w;
      t0o += a0.x * vo.x + a0.y * vo.y + a0.z * vo.z + a0.w * vo.w;
      t1o += a1.x * vo.x + a1.y * vo.y + a1.z * vo.z + a1.w * vo.w;
    }
    float wr0 = Wr[col * C_ + lane], wr1 = Wr[col * C_ + 64 + lane];
    float wa0 = Wsa[col * C_ + lane], wa1 = Wsa[col * C_ + 64 + lane];
    float wo0 = Wo[col * C_ + lane], wo1 = Wo[col * C_ + 64 + lane];
    float u0 = u[lane], u1 = u[64 + lane];
    float dR = wredsum(wr0 * t0r + wr1 * t1r);
    float pR = wredsum(wr0 * sx0 + wr1 * sx1);
    float dA = wredsum(wa0 * t0a + wa1 * t1a);
    float cA = wredsum(u0 * t0a + u1 * t1a);
    float pA = wredsum(wa0 * sx0 + wa1 * sx1);
    float dO = wredsum(wo0 * t0o + wo1 * t1o);
    float pO = wredsum(wo0 * sx0 + wo1 * sx1);
    float rl[N_];
#pragma unroll
    for (int n = 0; n < N_; ++n)
      rl[n] = wredsum(kn[n * C_ + lane] * t0r + kn[n * C_ + 64 + lane] * t1r);
    if (lane == 0) {
      diagR[b * C_ + col] = dR;  prv[b * C_ + col] = pR;
      diagSA[b * C_ + col] = dA; colsumSA[b * C_ + col] = cA; psav[b * C_ + col] = pA;
      diagO[b * C_ + col] = dO;  pov[b * C_ + col] = pO;
      for (int n = 0; n < N_; ++n) rel[(b * N_ + n) * C_ + col] = rl[n];
    }
  } else {
    const int n = col - C_;
    const float4* wk = (const float4*)(kn + n * C_);
    float t0 = 0, t1 = 0;
    for (int c = 0; c < 32; ++c) {
      float4 a0 = g0[c], a1 = g1[c], vk = wk[c];
      t0 += a0.x * vk.x + a0.y * vk.y + a0.z * vk.z + a0.w * vk.w;
      t1 += a1.x * vk.x + a1.y * vk.y + a1.z * vk.z + a1.w * vk.w;
    }
    float k0v = kn[n * C_ + lane], k1v = kn[n * C_ + 64 + lane];
    float dN = wredsum(k0v * t0 + k1v * t1);
    float kx = wredsum(k0v * sx0 + k1v * sx1);
    if (lane == 0) { diagN[b * N_ + n] = dN; ksx[b * N_ + n] = kx; }
  }
}

// ---------------- Kernel 3: per-batch assembly -> A[b,c], B[b,c] ------------
__global__ __launch_bounds__(128) void k_asm(
    const float* diagR, const float* diagSA, const float* colsumSA, const float* diagO,
    const float* prv, const float* psav, const float* pov,
    const float* rel, const float* diagN, const float* ksx,
    const float* br, const float* bo, const float* bsa, const float* alpha,
    float* Aout, float* Bout) {
  const int b = blockIdx.x;
  const int t = threadIdx.x;
  __shared__ float rb2[2];
  __shared__ float att_s[N_][C_ + 1];
  __shared__ float s1_s[C_], s2_s[C_];
  __shared__ float inv_s[N_], fmi_s[N_];
  const float hw = (float)HW_;
  const float bsa_c = bsa[t], br_c = br[t], bo_c = bo[t];
  const float psa_c = psav[b * C_ + t], pr_c = prv[b * C_ + t], po_c = pov[b * C_ + t];

  float bsum, psum, mx, ssum;
  { float wv = wredsum(bsa_c); if ((t & 63) == 0) rb2[t >> 6] = wv; __syncthreads();
    bsum = rb2[0] + rb2[1]; __syncthreads(); }
  { float wv = wredsum(psa_c); if ((t & 63) == 0) rb2[t >> 6] = wv; __syncthreads();
    psum = rb2[0] + rb2[1]; __syncthreads(); }

  const float nxr = sqrtf(fmaxf(diagR[b * C_ + t] + 2.f * br_c * pr_c + hw * br_c * br_c, 0.f));
  s1_s[t] = po_c + hw * bo_c;
  s2_s[t] = diagO[b * C_ + t] + 2.f * bo_c * po_c + hw * bo_c * bo_c;
  const float colsum = colsumSA[b * C_ + t] + bsum * psa_c + bsa_c * (psum + hw * bsum);
  const float diagv = diagSA[b * C_ + t] + 2.f * bsa_c * psa_c + hw * bsa_c * bsa_c;
  const float fm = (colsum - diagv) * (1.f / (float)C_);

  { float wv = wredmax(fm); if ((t & 63) == 0) rb2[t >> 6] = wv; __syncthreads();
    mx = fmaxf(rb2[0], rb2[1]); __syncthreads(); }
  const float ee = expf(fm - mx);
  { float wv = wredsum(ee); if ((t & 63) == 0) rb2[t >> 6] = wv; __syncthreads();
    ssum = rb2[0] + rb2[1]; __syncthreads(); }
  const float reg = ee / ssum;

  float r[N_];
  float rmax = -1e30f;
#pragma unroll
  for (int n = 0; n < N_; ++n) {
    float al = fminf(fmaxf(alpha[n], 0.f), 1.f);
    float nxn = sqrtf(fmaxf(diagN[b * N_ + n], 0.f));
    float rv = (rel[(b * N_ + n) * C_ + t] + br_c * ksx[b * N_ + n]) / (nxn * nxr + EPS_) + al * reg;
    r[n] = rv; rmax = fmaxf(rmax, rv);
  }
  float es = 0.f;
#pragma unroll
  for (int n = 0; n < N_; ++n) { r[n] = expf(r[n] - rmax); es += r[n]; }
  const float ies = 1.f / es;
#pragma unroll
  for (int n = 0; n < N_; ++n) att_s[n][t] = r[n] * ies;
  __syncthreads();

  if (t < N_) {
    float sa = 0.f, sh = 0.f, sq = 0.f;
    for (int c = 0; c < C_; ++c) {
      float a = att_s[t][c];
      sa += a; sh += a * s1_s[c]; sq += a * a * s2_s[c];
    }
    float cnt = sa * hw + EPS_;
    float fmean = sh / cnt;
    float sqv = sq - 2.f * fmean * sh + fmean * fmean * ((float)C_ * hw);
    float fstd = sqrtf(fmaxf(sqv, 0.f) / cnt);
    float inv = 1.f / (fstd + EPS_);
    inv_s[t] = inv; fmi_s[t] = fmean * inv;
  }
  __syncthreads();

  float Ac = 0.f, Bc = 0.f;
#pragma unroll
  for (int n = 0; n < N_; ++n) { float a = att_s[n][t]; Ac += a * inv_s[n]; Bc += a * fmi_s[n]; }
  Aout[b * C_ + t] = Ac; Bout[b * C_ + t] = Bc;
}

// ---------------- Kernel 4: out = x + sigma*((Wo x + bo)*A - B) -------------
// grid (64, 8), 256 threads, LB(256,3), ~53 KB LDS -> 3 blocks/CU.
// Wo staged ONCE per block into LDS from precomputed bf16 copy (no cvt).
// x tile staged transposed (Xt[p][c]) for single-b128 MFMA B-frags; x loads
// register-prefetched (v[8]) across pt iterations. Epilogue = round-2 scatter
// (proven ~35 us). pt loop NOT unrolled to keep VGPR pressure low (round-3
// lesson: af-in-registers spilled to scratch -> 330 MB HBM spill traffic).
#define WS2_ 136
#define XT_  136
__global__ __launch_bounds__(256, 3) void k_out(
    const float* __restrict__ x, const u16* __restrict__ wo_bf,
    const float* __restrict__ bo, const float* __restrict__ Aws,
    const float* __restrict__ Bws, const float* __restrict__ sig,
    float* __restrict__ out) {
  const int b = blockIdx.y;
  __shared__ u16 Wob[C_ * WS2_];   // 34816 B
  __shared__ u16 Xt[64 * XT_];     // 17408 B
  __shared__ float As[C_], Bs[C_], bos[C_];
  const int tid = threadIdx.x, lane = tid & 63, w = tid >> 6;
  const int n = lane & 15, q = lane >> 4;

  // stage Wo (bf16) into LDS: 8 B per thread per j
#pragma unroll
  for (int j = 0; j < 16; ++j) {
    int f = tid + 256 * j;            // 0..4095 four-u16 groups
    int o = f >> 5, c4 = f & 31;
    *(s4v*)(&Wob[o * WS2_ + 4 * c4]) = *(const s4v*)(wo_bf + o * C_ + 4 * c4);
  }
  if (tid < C_) { As[tid] = Aws[b * C_ + tid]; Bs[tid] = Bws[b * C_ + tid]; bos[tid] = bo[tid]; }
  const float sg = sig[0];

  const float* xb = x + (size_t)b * C_ * HW_;
  float* ob = out + (size_t)b * C_ * HW_;
  const int pq = tid & 15;           // cell geometry (cc in {0,1})
  const int c4a = tid >> 4;          // cell 0: c4 = c4a; cell 1: c4 = 16 + c4a

  float4 v[8];
  {
    const int p0 = blockIdx.x * 256;
#pragma unroll
    for (int cc = 0; cc < 2; ++cc) {
      const float* src = xb + (size_t)(4 * (16 * cc + c4a)) * HW_ + p0 + 4 * pq;
#pragma unroll
      for (int r2 = 0; r2 < 4; ++r2) v[4 * cc + r2] = *(const float4*)(src + (size_t)r2 * HW_);
    }
  }
  __syncthreads();

#pragma unroll 1
  for (int pt = 0; pt < 4; ++pt) {
    const int p0 = blockIdx.x * 256 + pt * 64;
    // transpose + convert + LDS write
#pragma unroll
    for (int cc = 0; cc < 2; ++cc) {
      const int c4 = 16 * cc + c4a;
      float4 v0 = v[4 * cc + 0], v1 = v[4 * cc + 1], v2 = v[4 * cc + 2], v3 = v[4 * cc + 3];
      s4v s0, s1, s2, s3;
      s0[0] = (short)f2b(v0.x); s0[1] = (short)f2b(v1.x); s0[2] = (short)f2b(v2.x); s0[3] = (short)f2b(v3.x);
      s1[0] = (short)f2b(v0.y); s1[1] = (short)f2b(v1.y); s1[2] = (short)f2b(v2.y); s1[3] = (short)f2b(v3.y);
      s2[0] = (short)f2b(v0.z); s2[1] = (short)f2b(v1.z); s2[2] = (short)f2b(v2.z); s2[3] = (short)f2b(v3.z);
      s3[0] = (short)f2b(v0.w); s3[1] = (short)f2b(v1.w); s3[2] = (short)f2b(v2.w); s3[3] = (short)f2b(v3.w);
      *(s4v*)(&Xt[(4 * pq + 0) * XT_ + 4 * c4]) = s0;
      *(s4v*)(&Xt[(4 * pq + 1) * XT_ + 4 * c4]) = s1;
      *(s4v*)(&Xt[(4 * pq + 2) * XT_ + 4 * c4]) = s2;
      *(s4v*)(&Xt[(4 * pq + 3) * XT_ + 4 * c4]) = s3;
    }
    __syncthreads();
    if (pt < 3) {  // prefetch next tile under MFMA
      const int pn = p0 + 64;
#pragma unroll
      for (int cc = 0; cc < 2; ++cc) {
        const float* src = xb + (size_t)(4 * (16 * cc + c4a)) * HW_ + pn + 4 * pq;
#pragma unroll
        for (int r2 = 0; r2 < 4; ++r2) v[4 * cc + r2] = *(const float4*)(src + (size_t)r2 * HW_);
      }
    }

    f4v acc[8];
#pragma unroll
    for (int a = 0; a < 8; ++a) acc[a] = (f4v){0.f, 0.f, 0.f, 0.f};
#pragma unroll
    for (int s = 0; s < 4; ++s) {
      s8v bfr = *(const s8v*)(&Xt[(w * 16 + n) * XT_ + 32 * s + 8 * q]);
#pragma unroll
      for (int a = 0; a < 8; ++a) {
        s8v af = *(const s8v*)(&Wob[(16 * a + n) * WS2_ + 32 * s + 8 * q]);
        acc[a] = __builtin_amdgcn_mfma_f32_16x16x32_bf16(af, bfr, acc[a], 0, 0, 0);
      }
    }

#pragma unroll
    for (int a = 0; a < 8; ++a)
#pragma unroll
      for (int r = 0; r < 4; ++r) {
        int o = 16 * a + 4 * q + r;
        size_t idx = (size_t)o * HW_ + p0 + w * 16 + n;
        float xo = acc[a][r] + bos[o];
        ob[idx] = xb[idx] + sg * (xo * As[o] - Bs[o]);
      }
    __syncthreads();
  }
}

extern "C" void kernel_launch(void* const* d_in, const int* in_sizes, int n_in,
                              void* d_out, int out_size, void* d_ws, size_t ws_size,
                              hipStream_t stream) {
  (void)in_sizes; (void)n_in; (void)out_size; (void)ws_size;
  const float* x     = (const float*)d_in[0];
  const float* Wsa   = (const float*)d_in[1];
  const float* bsa   = (const float*)d_in[2];
  const float* Wr    = (const float*)d_in[3];
  const float* br    = (const float*)d_in[4];
  const float* kn    = (const float*)d_in[5];
  const float* Wo    = (const float*)d_in[6];
  const float* bo    = (const float*)d_in[7];
  const float* alpha = (const float*)d_in[8];
  const float* sigma = (const float*)d_in[9];
  float* out = (float*)d_out;
  float* ws  = (float*)d_ws;

  float* G        = ws;            // 131072
  float* sx       = ws + 131072;   // 1024
  float* diagR    = ws + 132096;   // 1024
  float* diagSA   = ws + 133120;   // 1024
  float* colsumSA = ws + 134144;   // 1024
  float* diagO    = ws + 135168;   // 1024
  float* prv      = ws + 136192;   // 1024
  float* psav     = ws + 137216;   // 1024
  float* pov      = ws + 138240;   // 1024
  float* rel      = ws + 139264;   // 16384
  float* diagN    = ws + 155648;   // 128
  float* ksx      = ws + 155776;   // 128
  float* u        = ws + 155904;   // 128
  float* Aw       = ws + 156032;   // 1024
  float* Bw       = ws + 157056;   // 1024
  u16*   wo_bf    = (u16*)(ws + 158080);  // 16384 u16 = 8192 floats

  // d_out doubles as scratch for Gram partials until k_out overwrites it:
  float* pbuf = out;               // 64*8*16384 = 8388608 floats
  float* psx  = out + 8388608;     // 64*8*128   = 65536 floats

  k_gram<<<dim3(65, 8), 256, 0, stream>>>(x, pbuf, psx, Wsa, kn, Wo, u,
      out + (size_t)B_ * C_ * HW_, wo_bf);
  k_greduce<<<132, 256, 0, stream>>>((const float4*)pbuf, psx, (float4*)G, sx);
  k_cols<<<dim3(144, 8), 64, 0, stream>>>(G, sx, Wr, Wsa, Wo, kn, u,
      diagR, diagSA, colsumSA, diagO, prv, psav, pov, rel, diagN, ksx);
  k_asm<<<8, 128, 0, stream>>>(diagR, diagSA, colsumSA, diagO, prv, psav, pov,
      rel, diagN, ksx, br, bo, bsa, alpha, Aw, Bw);
  k_out<<<dim3(64, 8), 256, 0, stream>>>(x, wo_bf, bo, Aw, Bw, sigma, out);
}

// Round 5
// 180.942 us; speedup vs baseline: 1.5096x; 1.0298x over previous
//
#include <hip/hip_runtime.h>
#include <hip/hip_bf16.h>

#define B_   8
#define C_   128
#define HW_  16384
#define N_   16
#define EPS_ 1e-7f

typedef unsigned short u16;
typedef __attribute__((ext_vector_type(8))) short s8v;
typedef __attribute__((ext_vector_type(4))) short s4v;
typedef __attribute__((ext_vector_type(4))) float f4v;

__device__ __forceinline__ u16 f2b(float f) {
  union { __hip_bfloat16 b; u16 u; } cv; cv.b = __float2bfloat16(f); return cv.u;
}
__device__ __forceinline__ float b2f(u16 u) {
  union { float f; unsigned int i; } cv; cv.i = ((unsigned int)u) << 16; return cv.f;
}
__device__ __forceinline__ float wredsum(float v) {
#pragma unroll
  for (int o = 32; o > 0; o >>= 1) v += __shfl_xor(v, o, 64);
  return v;
}
__device__ __forceinline__ float wredmax(float v) {
#pragma unroll
  for (int o = 32; o > 0; o >>= 1) v = fmaxf(v, __shfl_xor(v, o, 64));
  return v;
}

// ---------------- Kernel 1: per-batch partial Gram + fused misc -------------
// 512 threads (8 waves), grid (65, 8), LB(512,4) -> 2 blocks/CU = 16 waves/CU
// (round-4 lesson: 256-thr blocks were grid-limited to 8 waves/CU and
// latency-bound at ~10 GB/s/CU). Wave w computes the 32x64 G quadrant
// rows (w&3)*32, cols (w>>2)*64. blockIdx.x==64 -> misc (u, orth, Wo->bf16).
#define XS_ 132  // LDS row stride in u16 (264 B): staging writes 2-way, reads ~2-way
__global__ __launch_bounds__(512, 4) void k_gram(
    const float* __restrict__ x, float* __restrict__ pbuf, float* __restrict__ psx,
    const float* __restrict__ Wsa, const float* __restrict__ kn,
    const float* __restrict__ Wo, float* __restrict__ u,
    float* __restrict__ loss_out, u16* __restrict__ wo_bf) {
  __shared__ u16 Xb[C_ * XS_];
  const int tid = threadIdx.x;
  const int b = blockIdx.y;

  if (blockIdx.x == 64) {  // ---- misc blocks ----
    if (b == 0) {          // u[r] = column sums of Wsa
      if (tid < C_) {
        float s = 0.f;
        for (int i = 0; i < C_; ++i) s += Wsa[i * C_ + tid];
        u[tid] = s;
      }
    } else if (b == 1) {   // orth loss (first 256 threads compute)
      float* smf = (float*)Xb;          // [0..15]=nrm, [16..23]=per-wave partials
      const int i = tid >> 4, j = tid & 15;
      float s = 0.f;
      if (tid < 256) {
        for (int c = 0; c < C_; ++c) s += kn[i * C_ + c] * kn[j * C_ + c];
        if (i == j) smf[i] = sqrtf(s);
      }
      __syncthreads();
      float l2 = 0.f;
      if (tid < 256) {
        float l = s / (smf[i] * smf[j] + EPS_) - (i == j ? 1.f : 0.f);
        l2 = l * l;
      }
      float wv = wredsum(l2);
      if ((tid & 63) == 0) smf[16 + (tid >> 6)] = wv;
      __syncthreads();
      if (tid == 0) {
        float t = 0.f;
        for (int k = 0; k < 8; ++k) t += smf[16 + k];
        loss_out[0] = 0.1f * logf(t + 1.f);
      }
    } else if (b == 2) {   // Wo -> bf16
#pragma unroll
      for (int j = 0; j < 8; ++j) {
        int f = tid + 512 * j;
        float4 v = ((const float4*)Wo)[f];
        s4v s; s[0] = (short)f2b(v.x); s[1] = (short)f2b(v.y);
        s[2] = (short)f2b(v.z); s[3] = (short)f2b(v.w);
        ((s4v*)wo_bf)[f] = s;
      }
    }
    return;
  }

  const int p0 = blockIdx.x * 256;
  const int lane = tid & 63;
  const int w = tid >> 6;                 // wave 0..7
  const int m = lane & 15, q = lane >> 4;
  const int rb = (w & 3) * 32, cb = (w >> 2) * 64;

  f4v acc[2][4];
#pragma unroll
  for (int a = 0; a < 2; ++a)
#pragma unroll
    for (int c2 = 0; c2 < 4; ++c2) acc[a][c2] = (f4v){0.f, 0.f, 0.f, 0.f};

  float sxp = 0.f;
  const float* xb = x + (size_t)b * C_ * HW_;
  const float* ro = xb + (size_t)(tid >> 5) * HW_ + p0 + 4 * (tid & 31);

  float4 v[8];
#pragma unroll
  for (int j = 0; j < 8; ++j) v[j] = *(const float4*)(ro + (size_t)(16 * j) * HW_);

#pragma unroll
  for (int t = 0; t < 2; ++t) {
    // convert + LDS write (rows c = (tid>>5)+16j, cols 4*(tid&31))
#pragma unroll
    for (int j = 0; j < 8; ++j) {
      int c = (tid >> 5) + 16 * j;
      s4v s; s[0] = (short)f2b(v[j].x); s[1] = (short)f2b(v[j].y);
      s[2] = (short)f2b(v[j].z); s[3] = (short)f2b(v[j].w);
      *(s4v*)(&Xb[c * XS_ + 4 * (tid & 31)]) = s;
    }
    __syncthreads();
    if (t == 0) {  // prefetch tile 1 under tile-0 compute
#pragma unroll
      for (int j = 0; j < 8; ++j) v[j] = *(const float4*)(ro + (size_t)(16 * j) * HW_ + 128);
    }
    if (tid < C_) {
#pragma unroll
      for (int kk = 0; kk < 16; ++kk) {
        s8v vv = *(const s8v*)(&Xb[tid * XS_ + 8 * kk]);
#pragma unroll
        for (int e = 0; e < 8; ++e) sxp += b2f((u16)vv[e]);
      }
    }
#pragma unroll
    for (int s = 0; s < 4; ++s) {
      const int k0 = 32 * s;
      s8v Af[2], Bf[4];
#pragma unroll
      for (int a = 0; a < 2; ++a)
        Af[a] = *(const s8v*)(&Xb[(rb + 16 * a + m) * XS_ + k0 + 8 * q]);
#pragma unroll
      for (int c2 = 0; c2 < 4; ++c2)
        Bf[c2] = *(const s8v*)(&Xb[(cb + 16 * c2 + m) * XS_ + k0 + 8 * q]);
#pragma unroll
      for (int a = 0; a < 2; ++a)
#pragma unroll
        for (int c2 = 0; c2 < 4; ++c2)
          acc[a][c2] = __builtin_amdgcn_mfma_f32_16x16x32_bf16(Af[a], Bf[c2], acc[a][c2], 0, 0, 0);
    }
    __syncthreads();
  }

  float* pg = pbuf + ((size_t)(blockIdx.x * B_ + b) << 14);
#pragma unroll
  for (int a = 0; a < 2; ++a)
#pragma unroll
    for (int c2 = 0; c2 < 4; ++c2)
#pragma unroll
      for (int r = 0; r < 4; ++r) {
        int row = rb + 16 * a + 4 * q + r;  // C/D: row=(lane>>4)*4+reg
        int col = cb + 16 * c2 + m;         //      col=lane&15
        pg[row * C_ + col] = acc[a][c2][r];
      }
  if (tid < C_) psx[(blockIdx.x * B_ + b) * C_ + tid] = sxp;
}

// ---------------- reduce 64 partials -> G, sx (float4) ----------------------
__global__ __launch_bounds__(256) void k_greduce(const float4* __restrict__ pbuf4,
                                                 const float* __restrict__ psx,
                                                 float4* __restrict__ G4,
                                                 float* __restrict__ sx) {
  const int blk = blockIdx.x;
  if (blk < 128) {
    const int gid = blk * 256 + threadIdx.x;  // [0, 32768)
    const int b = gid >> 12, idx4 = gid & 4095;
    float4 s = {0.f, 0.f, 0.f, 0.f};
#pragma unroll 16
    for (int ch = 0; ch < 64; ++ch) {
      float4 p = pbuf4[((size_t)(ch * B_ + b) << 12) + idx4];
      s.x += p.x; s.y += p.y; s.z += p.z; s.w += p.w;
    }
    G4[gid] = s;
  } else {
    const int tt = (blk - 128) * 256 + threadIdx.x;  // [0, 1024)
    const int b = tt >> 7, c = tt & 127;
    float s = 0.f;
#pragma unroll 16
    for (int ch = 0; ch < 64; ++ch) s += psx[(ch * B_ + b) * C_ + c];
    sx[tt] = s;
  }
}

// ---------------- Kernel 2: per-(batch, column) G-derived quantities --------
__global__ __launch_bounds__(64) void k_cols(
    const float* __restrict__ G, const float* __restrict__ sx,
    const float* __restrict__ Wr, const float* __restrict__ Wsa,
    const float* __restrict__ Wo, const float* __restrict__ kn,
    const float* __restrict__ u,
    float* diagR, float* diagSA, float* colsumSA, float* diagO,
    float* prv, float* psav, float* pov, float* rel, float* diagN, float* ksx) {
  const int b = blockIdx.y;
  const int col = blockIdx.x;
  const int lane = threadIdx.x;
  const float* Gb = G + b * C_ * C_;
  const float4* g0 = (const float4*)(Gb + lane * C_);
  const float4* g1 = (const float4*)(Gb + (64 + lane) * C_);
  const float sx0 = sx[b * C_ + lane], sx1 = sx[b * C_ + 64 + lane];

  if (col < C_) {
    const float4* wr = (const float4*)(Wr + col * C_);
    const float4* wa = (const float4*)(Wsa + col * C_);
    const float4* wo = (const float4*)(Wo + col * C_);
    float t0r = 0, t1r = 0, t0a = 0, t1a = 0, t0o = 0, t1o = 0;
    for (int c = 0; c < 32; ++c) {
      float4 a0 = g0[c], a1 = g1[c];
      float4 vr = wr[c], va = wa[c], vo = wo[c];
      t0r += a0.x * vr.x + a0.y * vr.y + a0.z * vr.z + a0.w * vr.w;
      t1r += a1.x * vr.x + a1.y * vr.y + a1.z * vr.z + a1.w * vr.w;
      t0a += a0.x * va.x + a0.y * va.y + a0.z * va.z + a0.w * va.w;
      t1a += a1.x * va.x + a1.y * va.y + a1.z * va.z + a1.w * va.w;
      t0o += a0.x * vo.x + a0.y * vo.y + a0.z * vo.z + a0.w * vo.w;
      t1o += a1.x * vo.x + a1.y * vo.y + a1.z * vo.z + a1.w * vo.w;
    }
    float wr0 = Wr[col * C_ + lane], wr1 = Wr[col * C_ + 64 + lane];
    float wa0 = Wsa[col * C_ + lane], wa1 = Wsa[col * C_ + 64 + lane];
    float wo0 = Wo[col * C_ + lane], wo1 = Wo[col * C_ + 64 + lane];
    float u0 = u[lane], u1 = u[64 + lane];
    float dR = wredsum(wr0 * t0r + wr1 * t1r);
    float pR = wredsum(wr0 * sx0 + wr1 * sx1);
    float dA = wredsum(wa0 * t0a + wa1 * t1a);
    float cA = wredsum(u0 * t0a + u1 * t1a);
    float pA = wredsum(wa0 * sx0 + wa1 * sx1);
    float dO = wredsum(wo0 * t0o + wo1 * t1o);
    float pO = wredsum(wo0 * sx0 + wo1 * sx1);
    float rl[N_];
#pragma unroll
    for (int n = 0; n < N_; ++n)
      rl[n] = wredsum(kn[n * C_ + lane] * t0r + kn[n * C_ + 64 + lane] * t1r);
    if (lane == 0) {
      diagR[b * C_ + col] = dR;  prv[b * C_ + col] = pR;
      diagSA[b * C_ + col] = dA; colsumSA[b * C_ + col] = cA; psav[b * C_ + col] = pA;
      diagO[b * C_ + col] = dO;  pov[b * C_ + col] = pO;
      for (int n = 0; n < N_; ++n) rel[(b * N_ + n) * C_ + col] = rl[n];
    }
  } else {
    const int n = col - C_;
    const float4* wk = (const float4*)(kn + n * C_);
    float t0 = 0, t1 = 0;
    for (int c = 0; c < 32; ++c) {
      float4 a0 = g0[c], a1 = g1[c], vk = wk[c];
      t0 += a0.x * vk.x + a0.y * vk.y + a0.z * vk.z + a0.w * vk.w;
      t1 += a1.x * vk.x + a1.y * vk.y + a1.z * vk.z + a1.w * vk.w;
    }
    float k0v = kn[n * C_ + lane], k1v = kn[n * C_ + 64 + lane];
    float dN = wredsum(k0v * t0 + k1v * t1);
    float kx = wredsum(k0v * sx0 + k1v * sx1);
    if (lane == 0) { diagN[b * N_ + n] = dN; ksx[b * N_ + n] = kx; }
  }
}

// ---------------- Kernel 3: per-batch assembly -> A[b,c], B[b,c] ------------
__global__ __launch_bounds__(128) void k_asm(
    const float* diagR, const float* diagSA, const float* colsumSA, const float* diagO,
    const float* prv, const float* psav, const float* pov,
    const float* rel, const float* diagN, const float* ksx,
    const float* br, const float* bo, const float* bsa, const float* alpha,
    float* Aout, float* Bout) {
  const int b = blockIdx.x;
  const int t = threadIdx.x;
  __shared__ float rb2[2];
  __shared__ float att_s[N_][C_ + 1];
  __shared__ float s1_s[C_], s2_s[C_];
  __shared__ float inv_s[N_], fmi_s[N_];
  const float hw = (float)HW_;
  const float bsa_c = bsa[t], br_c = br[t], bo_c = bo[t];
  const float psa_c = psav[b * C_ + t], pr_c = prv[b * C_ + t], po_c = pov[b * C_ + t];

  float bsum, psum, mx, ssum;
  { float wv = wredsum(bsa_c); if ((t & 63) == 0) rb2[t >> 6] = wv; __syncthreads();
    bsum = rb2[0] + rb2[1]; __syncthreads(); }
  { float wv = wredsum(psa_c); if ((t & 63) == 0) rb2[t >> 6] = wv; __syncthreads();
    psum = rb2[0] + rb2[1]; __syncthreads(); }

  const float nxr = sqrtf(fmaxf(diagR[b * C_ + t] + 2.f * br_c * pr_c + hw * br_c * br_c, 0.f));
  s1_s[t] = po_c + hw * bo_c;
  s2_s[t] = diagO[b * C_ + t] + 2.f * bo_c * po_c + hw * bo_c * bo_c;
  const float colsum = colsumSA[b * C_ + t] + bsum * psa_c + bsa_c * (psum + hw * bsum);
  const float diagv = diagSA[b * C_ + t] + 2.f * bsa_c * psa_c + hw * bsa_c * bsa_c;
  const float fm = (colsum - diagv) * (1.f / (float)C_);

  { float wv = wredmax(fm); if ((t & 63) == 0) rb2[t >> 6] = wv; __syncthreads();
    mx = fmaxf(rb2[0], rb2[1]); __syncthreads(); }
  const float ee = expf(fm - mx);
  { float wv = wredsum(ee); if ((t & 63) == 0) rb2[t >> 6] = wv; __syncthreads();
    ssum = rb2[0] + rb2[1]; __syncthreads(); }
  const float reg = ee / ssum;

  float r[N_];
  float rmax = -1e30f;
#pragma unroll
  for (int n = 0; n < N_; ++n) {
    float al = fminf(fmaxf(alpha[n], 0.f), 1.f);
    float nxn = sqrtf(fmaxf(diagN[b * N_ + n], 0.f));
    float rv = (rel[(b * N_ + n) * C_ + t] + br_c * ksx[b * N_ + n]) / (nxn * nxr + EPS_) + al * reg;
    r[n] = rv; rmax = fmaxf(rmax, rv);
  }
  float es = 0.f;
#pragma unroll
  for (int n = 0; n < N_; ++n) { r[n] = expf(r[n] - rmax); es += r[n]; }
  const float ies = 1.f / es;
#pragma unroll
  for (int n = 0; n < N_; ++n) att_s[n][t] = r[n] * ies;
  __syncthreads();

  if (t < N_) {
    float sa = 0.f, sh = 0.f, sq = 0.f;
    for (int c = 0; c < C_; ++c) {
      float a = att_s[t][c];
      sa += a; sh += a * s1_s[c]; sq += a * a * s2_s[c];
    }
    float cnt = sa * hw + EPS_;
    float fmean = sh / cnt;
    float sqv = sq - 2.f * fmean * sh + fmean * fmean * ((float)C_ * hw);
    float fstd = sqrtf(fmaxf(sqv, 0.f) / cnt);
    float inv = 1.f / (fstd + EPS_);
    inv_s[t] = inv; fmi_s[t] = fmean * inv;
  }
  __syncthreads();

  float Ac = 0.f, Bc = 0.f;
#pragma unroll
  for (int n = 0; n < N_; ++n) { float a = att_s[n][t]; Ac += a * inv_s[n]; Bc += a * fmi_s[n]; }
  Aout[b * C_ + t] = Ac; Bout[b * C_ + t] = Bc;
}

// ---------------- Kernel 4: out = x + sigma*((Wo x + bo)*A - B) -------------
// 512 threads (8 waves), grid (64, 8), LB(512,4) -> 2 blocks/CU = 16 waves/CU.
// Wave w owns o-rows [16w,16w+16): its Wo fragments are just af[4] (16 VGPRs),
// loaded ONCE from the bf16 Wo copy -> no Wob LDS (round-3 spill lesson:
// per-wave fragment footprint must be small). LDS = 17 KB transposed x-tile.
#define XT_ 132
__global__ __launch_bounds__(512, 4) void k_out(
    const float* __restrict__ x, const u16* __restrict__ wo_bf,
    const float* __restrict__ bo, const float* __restrict__ Aws,
    const float* __restrict__ Bws, const float* __restrict__ sig,
    float* __restrict__ out) {
  const int b = blockIdx.y;
  __shared__ u16 Xt[64 * XT_];     // 16896 B
  __shared__ float As[C_], Bs[C_], bos[C_];
  const int tid = threadIdx.x, lane = tid & 63, w = tid >> 6;  // wave 0..7
  const int n = lane & 15, q = lane >> 4;

  if (tid < C_) { As[tid] = Aws[b * C_ + tid]; Bs[tid] = Bws[b * C_ + tid]; bos[tid] = bo[tid]; }
  const float sg = sig[0];

  // per-wave Wo fragments: af[s] = Wo_bf16[16w+n][32s+8q .. +7]  (16 VGPRs)
  s8v af[4];
#pragma unroll
  for (int s = 0; s < 4; ++s)
    af[s] = *(const s8v*)(wo_bf + (16 * w + n) * C_ + 32 * s + 8 * q);

  const float* xb = x + (size_t)b * C_ * HW_;
  float* ob = out + (size_t)b * C_ * HW_;
  const int pq = tid & 15;           // p-quad 0..15
  const int c4 = tid >> 4;           // c-quad 0..31

  float4 v[4];
  {
    const int p0 = blockIdx.x * 256;
    const float* src = xb + (size_t)(4 * c4) * HW_ + p0 + 4 * pq;
#pragma unroll
    for (int r2 = 0; r2 < 4; ++r2) v[r2] = *(const float4*)(src + (size_t)r2 * HW_);
  }

#pragma unroll 1
  for (int pt = 0; pt < 4; ++pt) {
    const int p0 = blockIdx.x * 256 + pt * 64;
    // transpose + convert + LDS write: cell = 4c x 4p per thread
    {
      float4 v0 = v[0], v1 = v[1], v2 = v[2], v3 = v[3];
      s4v s0, s1, s2, s3;
      s0[0] = (short)f2b(v0.x); s0[1] = (short)f2b(v1.x); s0[2] = (short)f2b(v2.x); s0[3] = (short)f2b(v3.x);
      s1[0] = (short)f2b(v0.y); s1[1] = (short)f2b(v1.y); s1[2] = (short)f2b(v2.y); s1[3] = (short)f2b(v3.y);
      s2[0] = (short)f2b(v0.z); s2[1] = (short)f2b(v1.z); s2[2] = (short)f2b(v2.z); s2[3] = (short)f2b(v3.z);
      s3[0] = (short)f2b(v0.w); s3[1] = (short)f2b(v1.w); s3[2] = (short)f2b(v2.w); s3[3] = (short)f2b(v3.w);
      *(s4v*)(&Xt[(4 * pq + 0) * XT_ + 4 * c4]) = s0;
      *(s4v*)(&Xt[(4 * pq + 1) * XT_ + 4 * c4]) = s1;
      *(s4v*)(&Xt[(4 * pq + 2) * XT_ + 4 * c4]) = s2;
      *(s4v*)(&Xt[(4 * pq + 3) * XT_ + 4 * c4]) = s3;
    }
    __syncthreads();
    if (pt < 3) {  // prefetch next tile under MFMA
      const float* src = xb + (size_t)(4 * c4) * HW_ + p0 + 64 + 4 * pq;
#pragma unroll
      for (int r2 = 0; r2 < 4; ++r2) v[r2] = *(const float4*)(src + (size_t)r2 * HW_);
    }

    f4v acc[4];
#pragma unroll
    for (int p2 = 0; p2 < 4; ++p2) acc[p2] = (f4v){0.f, 0.f, 0.f, 0.f};
#pragma unroll
    for (int s = 0; s < 4; ++s) {
#pragma unroll
      for (int p2 = 0; p2 < 4; ++p2) {
        s8v bfr = *(const s8v*)(&Xt[(16 * p2 + n) * XT_ + 32 * s + 8 * q]);
        acc[p2] = __builtin_amdgcn_mfma_f32_16x16x32_bf16(af[s], bfr, acc[p2], 0, 0, 0);
      }
    }

#pragma unroll
    for (int p2 = 0; p2 < 4; ++p2)
#pragma unroll
      for (int r = 0; r < 4; ++r) {
        int o = 16 * w + 4 * q + r;
        size_t idx = (size_t)o * HW_ + p0 + 16 * p2 + n;
        float xo = acc[p2][r] + bos[o];
        ob[idx] = xb[idx] + sg * (xo * As[o] - Bs[o]);
      }
    __syncthreads();
  }
}

extern "C" void kernel_launch(void* const* d_in, const int* in_sizes, int n_in,
                              void* d_out, int out_size, void* d_ws, size_t ws_size,
                              hipStream_t stream) {
  (void)in_sizes; (void)n_in; (void)out_size; (void)ws_size;
  const float* x     = (const float*)d_in[0];
  const float* Wsa   = (const float*)d_in[1];
  const float* bsa   = (const float*)d_in[2];
  const float* Wr    = (const float*)d_in[3];
  const float* br    = (const float*)d_in[4];
  const float* kn    = (const float*)d_in[5];
  const float* Wo    = (const float*)d_in[6];
  const float* bo    = (const float*)d_in[7];
  const float* alpha = (const float*)d_in[8];
  const float* sigma = (const float*)d_in[9];
  float* out = (float*)d_out;
  float* ws  = (float*)d_ws;

  float* G        = ws;            // 131072
  float* sx       = ws + 131072;   // 1024
  float* diagR    = ws + 132096;   // 1024
  float* diagSA   = ws + 133120;   // 1024
  float* colsumSA = ws + 134144;   // 1024
  float* diagO    = ws + 135168;   // 1024
  float* prv      = ws + 136192;   // 1024
  float* psav     = ws + 137216;   // 1024
  float* pov      = ws + 138240;   // 1024
  float* rel      = ws + 139264;   // 16384
  float* diagN    = ws + 155648;   // 128
  float* ksx      = ws + 155776;   // 128
  float* u        = ws + 155904;   // 128
  float* Aw       = ws + 156032;   // 1024
  float* Bw       = ws + 157056;   // 1024
  u16*   wo_bf    = (u16*)(ws + 158080);  // 16384 u16 = 8192 floats

  // d_out doubles as scratch for Gram partials until k_out overwrites it:
  float* pbuf = out;               // 64*8*16384 = 8388608 floats
  float* psx  = out + 8388608;     // 64*8*128   = 65536 floats

  k_gram<<<dim3(65, 8), 512, 0, stream>>>(x, pbuf, psx, Wsa, kn, Wo, u,
      out + (size_t)B_ * C_ * HW_, wo_bf);
  k_greduce<<<132, 256, 0, stream>>>((const float4*)pbuf, psx, (float4*)G, sx);
  k_cols<<<dim3(144, 8), 64, 0, stream>>>(G, sx, Wr, Wsa, Wo, kn, u,
      diagR, diagSA, colsumSA, diagO, prv, psav, pov, rel, diagN, ksx);
  k_asm<<<8, 128, 0, stream>>>(diagR, diagSA, colsumSA, diagO, prv, psav, pov,
      rel, diagN, ksx, br, bo, bsa, alpha, Aw, Bw);
  k_out<<<dim3(64, 8), 512, 0, stream>>>(x, wo_bf, bo, Aw, Bw, sigma, out);
}